// Round 1
// baseline (2455.562 us; speedup 1.0000x reference)
//
#include <hip/hip_runtime.h>

typedef _Float16 f16;
typedef _Float16 half8 __attribute__((ext_vector_type(8)));
typedef _Float16 half4 __attribute__((ext_vector_type(4)));
typedef float floatx4 __attribute__((ext_vector_type(4)));

#define MFMA16(A, B, C) __builtin_amdgcn_mfma_f32_16x16x32_f16((A), (B), (C), 0, 0, 0)

// Problem constants
// B=128 N=1024 E=512 K=512 DICT=256

// ---------------- K0: Mt[j][i] = sum_k Wq[k][i] * Wk[k][j]  (512x512, fp32 acc -> fp16) -----
__global__ __launch_bounds__(256) void k_gemm_M(const float* __restrict__ Wq,
                                                const float* __restrict__ Wk,
                                                f16* __restrict__ Mt) {
  __shared__ __align__(16) float qa[16][64];
  __shared__ __align__(16) float kbs[16][64];
  const int tid = threadIdx.x;
  const int i0 = (blockIdx.x & 7) * 64;
  const int j0 = (blockIdx.x >> 3) * 64;
  const int tx = tid & 15, ty = tid >> 4;
  float acc[4][4] = {};
  for (int k0 = 0; k0 < 512; k0 += 16) {
    __syncthreads();
    const int kr = tid >> 4;
    const int c4 = (tid & 15) * 4;
    *(float4*)&qa[kr][c4]  = *(const float4*)&Wq[(k0 + kr) * 512 + i0 + c4];
    *(float4*)&kbs[kr][c4] = *(const float4*)&Wk[(k0 + kr) * 512 + j0 + c4];
    __syncthreads();
#pragma unroll
    for (int kk = 0; kk < 16; kk++) {
      float a[4], b[4];
#pragma unroll
      for (int x = 0; x < 4; x++) a[x] = qa[kk][ty * 4 + x];
#pragma unroll
      for (int y = 0; y < 4; y++) b[y] = kbs[kk][tx * 4 + y];
#pragma unroll
      for (int x = 0; x < 4; x++)
#pragma unroll
        for (int y = 0; y < 4; y++) acc[x][y] += a[x] * b[y];
    }
  }
#pragma unroll
  for (int x = 0; x < 4; x++)
#pragma unroll
    for (int y = 0; y < 4; y++)
      Mt[(j0 + tx * 4 + y) * 512 + (i0 + ty * 4 + x)] = (f16)acc[x][y];
}

// ---------------- K1: emb_h[b,n,e] = fp16(tok_emb[tok[b,n], e]) --------------------------
__global__ __launch_bounds__(256) void k_gather(const int* __restrict__ tok,
                                                const float* __restrict__ temb,
                                                f16* __restrict__ embh) {
  const long g = (long)blockIdx.x * 256 + threadIdx.x;
  const long flat = g * 8;
  const int row = (int)(flat >> 9);
  const int e0 = (int)(flat & 511);
  const int t = tok[row];
  const float4 v0 = *(const float4*)&temb[t * 512 + e0];
  const float4 v1 = *(const float4*)&temb[t * 512 + e0 + 4];
  half8 h;
  h[0] = (f16)v0.x; h[1] = (f16)v0.y; h[2] = (f16)v0.z; h[3] = (f16)v0.w;
  h[4] = (f16)v1.x; h[5] = (f16)v1.y; h[6] = (f16)v1.z; h[7] = (f16)v1.w;
  *(half8*)&embh[flat] = h;
}

// ---------------- K2: emb_t[b,e,n] = fp16(tok_emb[tok[b,n], e])  (transposed) -------------
__global__ __launch_bounds__(256) void k_gatherT(const int* __restrict__ tok,
                                                 const float* __restrict__ temb,
                                                 f16* __restrict__ embt) {
  __shared__ int tl[64];
  const int b = blockIdx.y;
  const int n0 = (blockIdx.x & 15) * 64;
  const int e0 = (blockIdx.x >> 4) * 128;
  const int tid = threadIdx.x;
  if (tid < 64) tl[tid] = tok[b * 1024 + n0 + tid];
  __syncthreads();
  const int n8 = (tid & 7) * 8;
  const int e4 = e0 + (tid >> 3) * 4;
  float4 v[8];
#pragma unroll
  for (int j = 0; j < 8; j++) v[j] = *(const float4*)&temb[tl[n8 + j] * 512 + e4];
#pragma unroll
  for (int a = 0; a < 4; a++) {
    half8 h;
#pragma unroll
    for (int j = 0; j < 8; j++) h[j] = (f16)((&v[j].x)[a]);
    *(half8*)&embt[(((long)(b * 512 + e4 + a)) << 10) + n0 + n8] = h;
  }
}

// ---------------- K3: T = emb_h[131072x512] @ M[512x512] -> fp16 (Mt is [n][k]) -----------
__global__ __launch_bounds__(256) void k_gemm_T(const f16* __restrict__ A,
                                                const f16* __restrict__ Bt,
                                                f16* __restrict__ T) {
  __shared__ __align__(16) f16 smem[17408];  // 34816 B
  f16* As = smem;          // 128 rows x 40 halves (32 + 8 pad)
  f16* Bs = smem + 5120;   // 128 rows x 40 halves
  const int tid = threadIdx.x;
  const long m0 = (long)blockIdx.y * 128;
  const int n0 = blockIdx.x * 128;
  const int w = tid >> 6, lane = tid & 63, lq = lane & 15, quad = lane >> 4;
  const int wm = w >> 1, wn = w & 1;
  floatx4 acc[4][4] = {};
  const int sr = tid >> 1, shc = (tid & 1) * 16;
  for (int k0 = 0; k0 < 512; k0 += 32) {
    half8 a0 = *(const half8*)&A[(m0 + sr) * 512 + k0 + shc];
    half8 a1 = *(const half8*)&A[(m0 + sr) * 512 + k0 + shc + 8];
    half8 b0 = *(const half8*)&Bt[(long)(n0 + sr) * 512 + k0 + shc];
    half8 b1 = *(const half8*)&Bt[(long)(n0 + sr) * 512 + k0 + shc + 8];
    __syncthreads();
    *(half8*)&As[sr * 40 + shc] = a0;
    *(half8*)&As[sr * 40 + shc + 8] = a1;
    *(half8*)&Bs[sr * 40 + shc] = b0;
    *(half8*)&Bs[sr * 40 + shc + 8] = b1;
    __syncthreads();
    half8 af[4], bf[4];
#pragma unroll
    for (int mt = 0; mt < 4; mt++) af[mt] = *(half8*)&As[(wm * 64 + mt * 16 + lq) * 40 + quad * 8];
#pragma unroll
    for (int nt = 0; nt < 4; nt++) bf[nt] = *(half8*)&Bs[(wn * 64 + nt * 16 + lq) * 40 + quad * 8];
#pragma unroll
    for (int mt = 0; mt < 4; mt++)
#pragma unroll
      for (int nt = 0; nt < 4; nt++) acc[mt][nt] = MFMA16(af[mt], bf[nt], acc[mt][nt]);
  }
  __syncthreads();
  // pack epilogue: rows 128 x 136 halves
  f16* Cp = smem;
#pragma unroll
  for (int mt = 0; mt < 4; mt++)
#pragma unroll
    for (int nt = 0; nt < 4; nt++)
#pragma unroll
      for (int rr = 0; rr < 4; rr++)
        Cp[(wm * 64 + mt * 16 + quad * 4 + rr) * 136 + wn * 64 + nt * 16 + lq] =
            (f16)acc[mt][nt][rr];
  __syncthreads();
  const int orow = tid >> 1, occ = (tid & 1) * 64;
#pragma unroll
  for (int i = 0; i < 8; i++) {
    half8 hv = *(half8*)&Cp[orow * 136 + occ + i * 8];
    *(half8*)&T[(m0 + orow) * 512 + n0 + occ + i * 8] = hv;
  }
}

// ---------------- K4: causal flash attention;  aff overwrites Tq in place ------------------
__global__ __launch_bounds__(256, 2) void k_attn(const f16* __restrict__ embh,
                                                 const f16* __restrict__ embt,
                                                 f16* tq_aff) {
  __shared__ __align__(16) f16 Ks[64 * 512];   // 64 KB, 16B-chunk xor-swizzled
  __shared__ __align__(16) f16 Pl[64 * 72];    // P rows padded to 72 halves
  __shared__ __align__(16) float alpha_s[64];
  __shared__ __align__(16) float l_s[64];
  const int tid = threadIdx.x;
  const int w = tid >> 6, lane = tid & 63, lq = lane & 15, quad = lane >> 4;
  const int b = blockIdx.y, qb = blockIdx.x;
  const int q0 = qb * 64;
  const long bOff = (long)b * 1024 * 512;

  // Q fragments in registers: lane holds Q[q = q0+w*16+lq][ks*32 + quad*8 + j]
  half8 qreg[16];
  {
    const f16* qrow = &tq_aff[bOff + (long)(q0 + w * 16 + lq) * 512];
#pragma unroll
    for (int t = 0; t < 16; t++) qreg[t] = *(const half8*)&qrow[t * 32 + quad * 8];
  }
  floatx4 Oa[4][8] = {};            // [q-tile 4][d-tile 8] (wave d-slice = w*128)
  float mrow = -1e30f, lrow = 0.f;  // stats for q = q0 + w*16 + lq

  for (int kb = 0; kb <= qb; kb++) {
    // ---- stage K-block rows into swizzled LDS
    {
      const int key = tid >> 2;
      const int gb = (tid & 3) * 16;
      const f16* src = &embh[bOff + (long)(kb * 64 + key) * 512];
#pragma unroll
      for (int i = 0; i < 16; i++) {
        int g = gb + i;
        int gs = (g & ~7) | ((g ^ key) & 7);
        half8 v = *(const half8*)&src[g * 8];
        *(half8*)&Ks[key * 512 + gs * 8] = v;
      }
    }
    __syncthreads();
    // ---- S^T = K @ Q^T : D[m=key][n=q]
    floatx4 st[4] = {};
#pragma unroll 4
    for (int ks = 0; ks < 16; ks++) {
#pragma unroll
      for (int mt = 0; mt < 4; mt++) {
        int key = mt * 16 + lq;
        int g = ks * 4 + quad;
        int gs = (g & ~7) | ((g ^ key) & 7);
        half8 af = *(half8*)&Ks[key * 512 + gs * 8];
        st[mt] = MFMA16(af, qreg[ks], st[mt]);
      }
    }
    // ---- mask + online softmax (per-lane stats for q = lq-col, reduce across quads)
    const int qg = q0 + w * 16 + lq;
    float sm = -1e30f;
    float sv[4][4];
#pragma unroll
    for (int mt = 0; mt < 4; mt++)
#pragma unroll
      for (int rr = 0; rr < 4; rr++) {
        int key = kb * 64 + mt * 16 + quad * 4 + rr;
        float s = st[mt][rr];
        if (key > qg) s = -1e30f;
        sv[mt][rr] = s;
        sm = fmaxf(sm, s);
      }
    sm = fmaxf(sm, __shfl_xor(sm, 16, 64));
    sm = fmaxf(sm, __shfl_xor(sm, 32, 64));
    const float mnew = fmaxf(mrow, sm);
    const float al = exp2f((mrow - mnew) * 1.44269504f);
    float psum = 0.f;
    f16 ph[4][4];
#pragma unroll
    for (int mt = 0; mt < 4; mt++)
#pragma unroll
      for (int rr = 0; rr < 4; rr++) {
        float p = exp2f((sv[mt][rr] - mnew) * 1.44269504f);
        psum += p;
        ph[mt][rr] = (f16)p;
      }
    psum += __shfl_xor(psum, 16, 64);
    psum += __shfl_xor(psum, 32, 64);
    lrow = lrow * al + psum;
    mrow = mnew;
    // ---- share P (rows = q, cols = key) and alpha
#pragma unroll
    for (int mt = 0; mt < 4; mt++) {
      half4 hp = {ph[mt][0], ph[mt][1], ph[mt][2], ph[mt][3]};
      *(half4*)&Pl[(w * 16 + lq) * 72 + mt * 16 + quad * 4] = hp;
    }
    if (lane < 16) alpha_s[w * 16 + lane] = al;
    __syncthreads();
    // ---- PV: rescale O, then O += P @ V  (V fragments streamed from emb_t)
    floatx4 alv[4];
#pragma unroll
    for (int mt = 0; mt < 4; mt++) alv[mt] = *(floatx4*)&alpha_s[mt * 16 + quad * 4];
#pragma unroll
    for (int mt = 0; mt < 4; mt++)
#pragma unroll
      for (int nt = 0; nt < 8; nt++) Oa[mt][nt] *= alv[mt];
    half8 ap[4][2];
#pragma unroll
    for (int mt = 0; mt < 4; mt++)
#pragma unroll
      for (int ks2 = 0; ks2 < 2; ks2++)
        ap[mt][ks2] = *(half8*)&Pl[(mt * 16 + lq) * 72 + ks2 * 32 + quad * 8];
#pragma unroll
    for (int ks2 = 0; ks2 < 2; ks2++)
#pragma unroll
      for (int nt = 0; nt < 8; nt++) {
        half8 bf = *(const half8*)&embt[(long)(b * 512 + w * 128 + nt * 16 + lq) * 1024 +
                                        kb * 64 + ks2 * 32 + quad * 8];
#pragma unroll
        for (int mt = 0; mt < 4; mt++) Oa[mt][nt] = MFMA16(ap[mt][ks2], bf, Oa[mt][nt]);
      }
    __syncthreads();
  }
  // ---- finalize: divide by l, pack through LDS, write aff (= Tq region, same rows)
  if (lane < 16) l_s[w * 16 + lane] = lrow;
  __syncthreads();
  floatx4 lv[4];
#pragma unroll
  for (int mt = 0; mt < 4; mt++) lv[mt] = *(floatx4*)&l_s[mt * 16 + quad * 4];
#pragma unroll
  for (int mt = 0; mt < 4; mt++)
#pragma unroll
    for (int nt = 0; nt < 8; nt++)
#pragma unroll
      for (int rr = 0; rr < 4; rr++) {
        float o = Oa[mt][nt][rr] / lv[mt][rr];
        Ks[(mt * 16 + quad * 4 + rr) * 512 + w * 128 + nt * 16 + lq] = (f16)o;
      }
  __syncthreads();
  const int orow = tid >> 2, ocb = (tid & 3) * 128;
#pragma unroll
  for (int i = 0; i < 16; i++) {
    half8 v = *(half8*)&Ks[orow * 512 + ocb + i * 8];
    *(half8*)&tq_aff[bOff + (long)(q0 + orow) * 512 + ocb + i * 8] = v;
  }
}

// ---------------- K5: split-K output GEMM: partial[blk] = aff[:,chunk] @ Wl[:,chunk]^T ----
__global__ __launch_bounds__(256) void k_out_partial(const f16* __restrict__ aff,
                                                     const float* __restrict__ Wl,
                                                     float* __restrict__ part) {
  __shared__ __align__(16) f16 smem[15360];  // As 128x40, Bs 256x40
  f16* As = smem;
  f16* Bs = smem + 5120;
  const int tid = threadIdx.x;
  const int w = tid >> 6, lane = tid & 63, lq = lane & 15, quad = lane >> 4;
  const int wm = w >> 1, wn = w & 1;
  const long kbase = (long)blockIdx.x * 1024;
  floatx4 acc[4][8] = {};
  const int rA = tid >> 1, hcA = (tid & 1) * 16;
  for (int k0 = 0; k0 < 1024; k0 += 32) {
    const long kk = kbase + k0;
    half8 a0 = *(const half8*)&aff[(long)rA * 524288 + kk + hcA];
    half8 a1 = *(const half8*)&aff[(long)rA * 524288 + kk + hcA + 8];
    float4 b4[8];
    const float* wrow = &Wl[(long)tid * 524288 + kk];
#pragma unroll
    for (int i = 0; i < 8; i++) b4[i] = *(const float4*)&wrow[i * 4];
    __syncthreads();
    *(half8*)&As[rA * 40 + hcA] = a0;
    *(half8*)&As[rA * 40 + hcA + 8] = a1;
#pragma unroll
    for (int j = 0; j < 4; j++) {
      half8 hb;
#pragma unroll
      for (int t = 0; t < 8; t++) hb[t] = (f16)((&b4[0].x)[j * 8 + t]);
      *(half8*)&Bs[tid * 40 + j * 8] = hb;
    }
    __syncthreads();
    half8 af[4], bf[8];
#pragma unroll
    for (int mt = 0; mt < 4; mt++) af[mt] = *(half8*)&As[(wm * 64 + mt * 16 + lq) * 40 + quad * 8];
#pragma unroll
    for (int nt = 0; nt < 8; nt++) bf[nt] = *(half8*)&Bs[(wn * 128 + nt * 16 + lq) * 40 + quad * 8];
#pragma unroll
    for (int mt = 0; mt < 4; mt++)
#pragma unroll
      for (int nt = 0; nt < 8; nt++) acc[mt][nt] = MFMA16(af[mt], bf[nt], acc[mt][nt]);
  }
  float* po = part + (long)blockIdx.x * 32768;
#pragma unroll
  for (int mt = 0; mt < 4; mt++)
#pragma unroll
    for (int nt = 0; nt < 8; nt++)
#pragma unroll
      for (int rr = 0; rr < 4; rr++)
        po[(wm * 64 + mt * 16 + quad * 4 + rr) * 256 + wn * 128 + nt * 16 + lq] =
            acc[mt][nt][rr];
}

// ---------------- K6: out = sum_p partial[p] + b_lin -------------------------------------
__global__ __launch_bounds__(256) void k_reduce(const float* __restrict__ part,
                                                const float* __restrict__ bl,
                                                float* __restrict__ out) {
  const int idx = blockIdx.x * 256 + threadIdx.x;
  float s = bl[idx & 255];
  for (int p = 0; p < 512; p++) s += part[(long)p * 32768 + idx];
  out[idx] = s;
}

extern "C" void kernel_launch(void* const* d_in, const int* in_sizes, int n_in,
                              void* d_out, int out_size, void* d_ws, size_t ws_size,
                              hipStream_t stream) {
  (void)in_sizes; (void)n_in; (void)out_size; (void)ws_size;
  const int* tok = (const int*)d_in[0];
  const float* temb = (const float*)d_in[1];
  const float* Wq = (const float*)d_in[2];
  const float* Wk = (const float*)d_in[3];
  // d_in[4] = Wv : computed-but-unused in the reference
  const float* Wl = (const float*)d_in[5];
  const float* bl = (const float*)d_in[6];
  float* out = (float*)d_out;
  char* ws = (char*)d_ws;

  f16* embh = (f16*)(ws);                    // 128 MB [B,N,E] fp16
  f16* embt = (f16*)(ws + 134217728L);       // 128 MB [B,E,N] fp16
  f16* Tq = (f16*)(ws + 268435456L);         // 128 MB [B*N,K] fp16; overwritten by aff in K4
  f16* Mt = (f16*)(ws + 402653184L);         // 512 KB [n][k] fp16
  float* part = (float*)(ws);                // 64 MB, overlays embh (dead after K4)

  hipLaunchKernelGGL(k_gemm_M, dim3(64), dim3(256), 0, stream, Wq, Wk, Mt);
  hipLaunchKernelGGL(k_gather, dim3(32768), dim3(256), 0, stream, tok, temb, embh);
  hipLaunchKernelGGL(k_gatherT, dim3(64, 128), dim3(256), 0, stream, tok, temb, embt);
  hipLaunchKernelGGL(k_gemm_T, dim3(4, 1024), dim3(256), 0, stream, embh, Mt, Tq);
  hipLaunchKernelGGL(k_attn, dim3(16, 128), dim3(256), 0, stream, embh, embt, Tq);
  hipLaunchKernelGGL(k_out_partial, dim3(512), dim3(256), 0, stream, Tq, Wl, part);
  hipLaunchKernelGGL(k_reduce, dim3(128), dim3(256), 0, stream, part, bl, out);
}

// Round 2
// 2236.654 us; speedup vs baseline: 1.0979x; 1.0979x over previous
//
#include <hip/hip_runtime.h>

typedef _Float16 f16;
typedef _Float16 half8 __attribute__((ext_vector_type(8)));
typedef _Float16 half4 __attribute__((ext_vector_type(4)));
typedef float floatx4 __attribute__((ext_vector_type(4)));
typedef float floatx16 __attribute__((ext_vector_type(16)));

#define MFMA16(A, B, C) __builtin_amdgcn_mfma_f32_16x16x32_f16((A), (B), (C), 0, 0, 0)
#define MFMA32(A, B, C) __builtin_amdgcn_mfma_f32_32x32x16_f16((A), (B), (C), 0, 0, 0)

// Problem constants: B=128 N=1024 E=512 K=512 DICT=256

// ---------------- K0: Mt[j][i] = sum_k Wq[k][i] * Wk[k][j]  (512x512, fp32 acc -> fp16) -----
__global__ __launch_bounds__(256) void k_gemm_M(const float* __restrict__ Wq,
                                                const float* __restrict__ Wk,
                                                f16* __restrict__ Mt) {
  __shared__ __align__(16) float qa[16][64];
  __shared__ __align__(16) float kbs[16][64];
  const int tid = threadIdx.x;
  const int i0 = (blockIdx.x & 7) * 64;
  const int j0 = (blockIdx.x >> 3) * 64;
  const int tx = tid & 15, ty = tid >> 4;
  float acc[4][4] = {};
  for (int k0 = 0; k0 < 512; k0 += 16) {
    __syncthreads();
    const int kr = tid >> 4;
    const int c4 = (tid & 15) * 4;
    *(float4*)&qa[kr][c4]  = *(const float4*)&Wq[(k0 + kr) * 512 + i0 + c4];
    *(float4*)&kbs[kr][c4] = *(const float4*)&Wk[(k0 + kr) * 512 + j0 + c4];
    __syncthreads();
#pragma unroll
    for (int kk = 0; kk < 16; kk++) {
      float a[4], b[4];
#pragma unroll
      for (int x = 0; x < 4; x++) a[x] = qa[kk][ty * 4 + x];
#pragma unroll
      for (int y = 0; y < 4; y++) b[y] = kbs[kk][tx * 4 + y];
#pragma unroll
      for (int x = 0; x < 4; x++)
#pragma unroll
        for (int y = 0; y < 4; y++) acc[x][y] += a[x] * b[y];
    }
  }
#pragma unroll
  for (int x = 0; x < 4; x++)
#pragma unroll
    for (int y = 0; y < 4; y++)
      Mt[(j0 + tx * 4 + y) * 512 + (i0 + ty * 4 + x)] = (f16)acc[x][y];
}

// ---------------- K1: emb_h[b,n,e] = fp16(tok_emb[tok[b,n], e]) --------------------------
__global__ __launch_bounds__(256) void k_gather(const int* __restrict__ tok,
                                                const float* __restrict__ temb,
                                                f16* __restrict__ embh) {
  const long g = (long)blockIdx.x * 256 + threadIdx.x;
  const long flat = g * 8;
  const int row = (int)(flat >> 9);
  const int e0 = (int)(flat & 511);
  const int t = tok[row];
  const float4 v0 = *(const float4*)&temb[t * 512 + e0];
  const float4 v1 = *(const float4*)&temb[t * 512 + e0 + 4];
  half8 h;
  h[0] = (f16)v0.x; h[1] = (f16)v0.y; h[2] = (f16)v0.z; h[3] = (f16)v0.w;
  h[4] = (f16)v1.x; h[5] = (f16)v1.y; h[6] = (f16)v1.z; h[7] = (f16)v1.w;
  *(half8*)&embh[flat] = h;
}

// ---------------- K2: emb_t[b,e,n] = fp16(tok_emb[tok[b,n], e])  (transposed) -------------
__global__ __launch_bounds__(256) void k_gatherT(const int* __restrict__ tok,
                                                 const float* __restrict__ temb,
                                                 f16* __restrict__ embt) {
  __shared__ int tl[64];
  const int b = blockIdx.y;
  const int n0 = (blockIdx.x & 15) * 64;
  const int e0 = (blockIdx.x >> 4) * 128;
  const int tid = threadIdx.x;
  if (tid < 64) tl[tid] = tok[b * 1024 + n0 + tid];
  __syncthreads();
  const int n8 = (tid & 7) * 8;
  const int e4 = e0 + (tid >> 3) * 4;
  float4 v[8];
#pragma unroll
  for (int j = 0; j < 8; j++) v[j] = *(const float4*)&temb[tl[n8 + j] * 512 + e4];
#pragma unroll
  for (int a = 0; a < 4; a++) {
    half8 h;
#pragma unroll
    for (int j = 0; j < 8; j++) h[j] = (f16)((&v[j].x)[a]);
    *(half8*)&embt[(((long)(b * 512 + e4 + a)) << 10) + n0 + n8] = h;
  }
}

// ---------------- K3: T = emb_h[131072x512] @ M[512x512] -> fp16 (Mt is [n][k]) -----------
__global__ __launch_bounds__(256) void k_gemm_T(const f16* __restrict__ A,
                                                const f16* __restrict__ Bt,
                                                f16* __restrict__ T) {
  __shared__ __align__(16) f16 smem[17408];
  f16* As = smem;          // 128 rows x 40 halves
  f16* Bs = smem + 5120;   // 128 rows x 40 halves
  const int tid = threadIdx.x;
  const long m0 = (long)blockIdx.y * 128;
  const int n0 = blockIdx.x * 128;
  const int w = tid >> 6, lane = tid & 63, lq = lane & 15, quad = lane >> 4;
  const int wm = w >> 1, wn = w & 1;
  floatx4 acc[4][4] = {};
  const int sr = tid >> 1, shc = (tid & 1) * 16;
  for (int k0 = 0; k0 < 512; k0 += 32) {
    half8 a0 = *(const half8*)&A[(m0 + sr) * 512 + k0 + shc];
    half8 a1 = *(const half8*)&A[(m0 + sr) * 512 + k0 + shc + 8];
    half8 b0 = *(const half8*)&Bt[(long)(n0 + sr) * 512 + k0 + shc];
    half8 b1 = *(const half8*)&Bt[(long)(n0 + sr) * 512 + k0 + shc + 8];
    __syncthreads();
    *(half8*)&As[sr * 40 + shc] = a0;
    *(half8*)&As[sr * 40 + shc + 8] = a1;
    *(half8*)&Bs[sr * 40 + shc] = b0;
    *(half8*)&Bs[sr * 40 + shc + 8] = b1;
    __syncthreads();
    half8 af[4], bf[4];
#pragma unroll
    for (int mt = 0; mt < 4; mt++) af[mt] = *(half8*)&As[(wm * 64 + mt * 16 + lq) * 40 + quad * 8];
#pragma unroll
    for (int nt = 0; nt < 4; nt++) bf[nt] = *(half8*)&Bs[(wn * 64 + nt * 16 + lq) * 40 + quad * 8];
#pragma unroll
    for (int mt = 0; mt < 4; mt++)
#pragma unroll
      for (int nt = 0; nt < 4; nt++) acc[mt][nt] = MFMA16(af[mt], bf[nt], acc[mt][nt]);
  }
  __syncthreads();
  f16* Cp = smem;
#pragma unroll
  for (int mt = 0; mt < 4; mt++)
#pragma unroll
    for (int nt = 0; nt < 4; nt++)
#pragma unroll
      for (int rr = 0; rr < 4; rr++)
        Cp[(wm * 64 + mt * 16 + quad * 4 + rr) * 136 + wn * 64 + nt * 16 + lq] =
            (f16)acc[mt][nt][rr];
  __syncthreads();
  const int orow = tid >> 1, occ = (tid & 1) * 64;
#pragma unroll
  for (int i = 0; i < 8; i++) {
    half8 hv = *(half8*)&Cp[orow * 136 + occ + i * 8];
    *(half8*)&T[(m0 + orow) * 512 + n0 + occ + i * 8] = hv;
  }
}

// ---------------- K4 v2: causal flash attention, 32x32x16 MFMA, all-LDS operands ----------
// Block: 256 thr (4 waves), Q-tile 64, K-tile 64, 1 block/CU (142 KB LDS).
// Wave roles: QK quadrant (mh=w&1 keys, nh=w>>1 queries); PV e-slice w*128.
__global__ __launch_bounds__(256, 1) void k_attn2(const f16* __restrict__ embh,
                                                  const f16* __restrict__ embt,
                                                  f16* tq_aff) {
  __shared__ __align__(16) f16 smem[70144];
  f16* Ks = smem;            // [64 key][512 e], 16B-chunk xor-swizzled (64 KB)
  f16* Vt = smem + 32768;    // [512 e][64 key], xor-swizzled (64 KB)
  f16* Pl = smem + 65536;    // [64 q][72] (pad 8)
  __shared__ __align__(16) float wmax[4][32];
  __shared__ __align__(16) float wsum[4][32];
  __shared__ __align__(16) float alpha_s[64];
  __shared__ __align__(16) float l_s[64];

  const int tid = threadIdx.x;
  const int w = tid >> 6, lane = tid & 63;
  const int l31 = lane & 31, lh = lane >> 5;
  const int mh = w & 1, nh = w >> 1;

  // XCD swizzle: 16 consecutive slots on one XCD = one batch's 16 q-blocks -> L2 reuse
  const int bid = blockIdx.x;
  const int xcd = bid & 7, idx = bid >> 3;
  const int b = xcd * 16 + (idx >> 4);
  const int qb = idx & 15;
  const int q0 = qb * 64;
  const long bOff = (long)b * 1024 * 512;

  // Q fragments in registers: lane holds Q[q=q0+nh*32+l31][kc*16 + lh*8 + j]
  half8 qreg[32];
  {
    const f16* qrow = &tq_aff[bOff + (long)(q0 + nh * 32 + l31) * 512];
#pragma unroll
    for (int kc = 0; kc < 32; kc++) qreg[kc] = *(const half8*)&qrow[kc * 16 + lh * 8];
  }
  floatx16 Oa[2][4] = {};           // O[64q][128e] per wave: [mt][nt]
  float mrow = -1e30f, lrow = 0.f;  // stats for q = qcol (lh-duplicated)
  const int qcol = q0 + nh * 32 + l31;

  for (int kb = 0; kb <= qb; kb++) {
    __syncthreads();  // A: prior PV reads done before restage
    {  // stage Ks: 64 rows x 1024B; thread: row=tid&63, chunk-quarter=tid>>6
      const int key = tid & 63, qo = tid >> 6;
      const f16* src = &embh[bOff + (long)(kb * 64 + key) * 512];
#pragma unroll
      for (int i = 0; i < 16; i++) {
        int g = qo * 16 + i;
        int gs = (g & ~7) | ((g ^ key) & 7);
        *(half8*)&Ks[key * 512 + gs * 8] = *(const half8*)&src[g * 8];
      }
    }
    {  // stage Vt: 512 rows x 128B; 8 threads/row (coalesced 128B), 16 passes
      const int ch = tid & 7, er = tid >> 3;
#pragma unroll
      for (int p = 0; p < 16; p++) {
        int e = p * 32 + er;
        int gs = ch ^ (e & 7);
        *(half8*)&Vt[e * 64 + gs * 8] =
            *(const half8*)&embt[((long)(b * 512 + e) << 10) + kb * 64 + ch * 8];
      }
    }
    __syncthreads();  // B: stage complete
    // ---- QK: S^T quadrant [32 keys x 32 q], contraction 512 e = 32 chunks
    floatx16 st = {};
    const int key = mh * 32 + l31;
#pragma unroll
    for (int kc = 0; kc < 32; kc++) {
      int g = kc * 2 + lh;
      int gs = (g & ~7) | ((g ^ key) & 7);
      half8 a = *(half8*)&Ks[key * 512 + gs * 8];
      st = MFMA32(a, qreg[kc], st);
    }
    // ---- mask + per-lane partial stats (lane holds 16 keys for q=qcol)
    float sv[16];
    float pm = -1e30f;
#pragma unroll
    for (int r = 0; r < 16; r++) {
      int keyr = kb * 64 + mh * 32 + (r & 3) + 8 * (r >> 2) + 4 * lh;
      float s = st[r];
      if (keyr > qcol) s = -1e30f;
      sv[r] = s;
      pm = fmaxf(pm, s);
    }
    pm = fmaxf(pm, __shfl_xor(pm, 32, 64));
    if (lane < 32) wmax[w][lane] = pm;
    __syncthreads();  // C: partial maxima exchanged
    const float tmax = fmaxf(wmax[nh * 2][l31], wmax[nh * 2 + 1][l31]);
    const float mnew = fmaxf(mrow, tmax);
    const float al = exp2f((mrow - mnew) * 1.44269504f);
    float psum = 0.f;
    f16 ph[16];
#pragma unroll
    for (int r = 0; r < 16; r++) {
      float p = exp2f((sv[r] - mnew) * 1.44269504f);
      psum += p;
      ph[r] = (f16)p;
    }
    psum += __shfl_xor(psum, 32, 64);
    if (lane < 32) wsum[w][lane] = psum;
    if (mh == 0 && lane < 32) alpha_s[nh * 32 + lane] = al;
    // write P: reg groups of 4 = contiguous keys
#pragma unroll
    for (int grp = 0; grp < 4; grp++) {
      half4 hp = {ph[grp * 4 + 0], ph[grp * 4 + 1], ph[grp * 4 + 2], ph[grp * 4 + 3]};
      *(half4*)&Pl[(nh * 32 + l31) * 72 + mh * 32 + grp * 8 + lh * 4] = hp;
    }
    mrow = mnew;
    __syncthreads();  // D: P / wsum / alpha ready
    lrow = lrow * al + wsum[nh * 2][l31] + wsum[nh * 2 + 1][l31];
    // ---- rescale O by alpha (row-indexed float4 broadcasts)
#pragma unroll
    for (int mt = 0; mt < 2; mt++)
#pragma unroll
      for (int grp = 0; grp < 4; grp++) {
        floatx4 av = *(floatx4*)&alpha_s[mt * 32 + grp * 8 + lh * 4];
#pragma unroll
        for (int nt = 0; nt < 4; nt++)
#pragma unroll
          for (int j = 0; j < 4; j++) Oa[mt][nt][grp * 4 + j] *= av[j];
      }
    // ---- PV: O[64q][128e] += P[64q][64k] @ V[64k][128e]
#pragma unroll
    for (int kc = 0; kc < 4; kc++) {
      half8 ap0 = *(half8*)&Pl[l31 * 72 + kc * 16 + lh * 8];
      half8 ap1 = *(half8*)&Pl[(32 + l31) * 72 + kc * 16 + lh * 8];
#pragma unroll
      for (int nt = 0; nt < 4; nt++) {
        int e = w * 128 + nt * 32 + l31;
        int g = kc * 2 + lh;
        int gs = g ^ (e & 7);
        half8 bv = *(half8*)&Vt[e * 64 + gs * 8];
        Oa[0][nt] = MFMA32(ap0, bv, Oa[0][nt]);
        Oa[1][nt] = MFMA32(ap1, bv, Oa[1][nt]);
      }
    }
  }
  if (mh == 0 && lane < 32) l_s[nh * 32 + lane] = lrow;
  __syncthreads();
  // ---- epilogue: divide by l, pack f16 into LDS [64][520], coalesced write-out
  f16* Ob = smem;
#pragma unroll
  for (int mt = 0; mt < 2; mt++)
#pragma unroll
    for (int grp = 0; grp < 4; grp++) {
      floatx4 lv = *(floatx4*)&l_s[mt * 32 + grp * 8 + lh * 4];
#pragma unroll
      for (int nt = 0; nt < 4; nt++) {
        int col = w * 128 + nt * 32 + l31;
#pragma unroll
        for (int j = 0; j < 4; j++) {
          int row = mt * 32 + grp * 8 + lh * 4 + j;
          Ob[row * 520 + col] = (f16)(Oa[mt][nt][grp * 4 + j] / lv[j]);
        }
      }
    }
  __syncthreads();
  {
    const int row = tid >> 2, seg = tid & 3;
#pragma unroll
    for (int i = 0; i < 16; i++) {
      half8 v = *(half8*)&Ob[row * 520 + seg * 128 + i * 8];
      *(half8*)&tq_aff[bOff + (long)(q0 + row) * 512 + seg * 128 + i * 8] = v;
    }
  }
}

// ---------------- K5: split-K output GEMM: partial[blk] = aff[:,chunk] @ Wl[:,chunk]^T ----
__global__ __launch_bounds__(256) void k_out_partial(const f16* __restrict__ aff,
                                                     const float* __restrict__ Wl,
                                                     float* __restrict__ part) {
  __shared__ __align__(16) f16 smem[15360];
  f16* As = smem;
  f16* Bs = smem + 5120;
  const int tid = threadIdx.x;
  const int w = tid >> 6, lane = tid & 63, lq = lane & 15, quad = lane >> 4;
  const int wm = w >> 1, wn = w & 1;
  const long kbase = (long)blockIdx.x * 1024;
  floatx4 acc[4][8] = {};
  const int rA = tid >> 1, hcA = (tid & 1) * 16;
  for (int k0 = 0; k0 < 1024; k0 += 32) {
    const long kk = kbase + k0;
    half8 a0 = *(const half8*)&aff[(long)rA * 524288 + kk + hcA];
    half8 a1 = *(const half8*)&aff[(long)rA * 524288 + kk + hcA + 8];
    float4 b4[8];
    const float* wrow = &Wl[(long)tid * 524288 + kk];
#pragma unroll
    for (int i = 0; i < 8; i++) b4[i] = *(const float4*)&wrow[i * 4];
    __syncthreads();
    *(half8*)&As[rA * 40 + hcA] = a0;
    *(half8*)&As[rA * 40 + hcA + 8] = a1;
#pragma unroll
    for (int j = 0; j < 4; j++) {
      half8 hb;
#pragma unroll
      for (int t = 0; t < 8; t++) hb[t] = (f16)((&b4[0].x)[j * 8 + t]);
      *(half8*)&Bs[tid * 40 + j * 8] = hb;
    }
    __syncthreads();
    half8 af[4], bf[8];
#pragma unroll
    for (int mt = 0; mt < 4; mt++) af[mt] = *(half8*)&As[(wm * 64 + mt * 16 + lq) * 40 + quad * 8];
#pragma unroll
    for (int nt = 0; nt < 8; nt++) bf[nt] = *(half8*)&Bs[(wn * 128 + nt * 16 + lq) * 40 + quad * 8];
#pragma unroll
    for (int mt = 0; mt < 4; mt++)
#pragma unroll
      for (int nt = 0; nt < 8; nt++) acc[mt][nt] = MFMA16(af[mt], bf[nt], acc[mt][nt]);
  }
  float* po = part + (long)blockIdx.x * 32768;
#pragma unroll
  for (int mt = 0; mt < 4; mt++)
#pragma unroll
    for (int nt = 0; nt < 8; nt++)
#pragma unroll
      for (int rr = 0; rr < 4; rr++)
        po[(wm * 64 + mt * 16 + quad * 4 + rr) * 256 + wn * 128 + nt * 16 + lq] =
            acc[mt][nt][rr];
}

// ---------------- K6: out = sum_p partial[p] + b_lin -------------------------------------
__global__ __launch_bounds__(256) void k_reduce(const float* __restrict__ part,
                                                const float* __restrict__ bl,
                                                float* __restrict__ out) {
  const int idx = blockIdx.x * 256 + threadIdx.x;
  float s = bl[idx & 255];
  for (int p = 0; p < 512; p++) s += part[(long)p * 32768 + idx];
  out[idx] = s;
}

extern "C" void kernel_launch(void* const* d_in, const int* in_sizes, int n_in,
                              void* d_out, int out_size, void* d_ws, size_t ws_size,
                              hipStream_t stream) {
  (void)in_sizes; (void)n_in; (void)out_size; (void)ws_size;
  const int* tok = (const int*)d_in[0];
  const float* temb = (const float*)d_in[1];
  const float* Wq = (const float*)d_in[2];
  const float* Wk = (const float*)d_in[3];
  // d_in[4] = Wv : computed-but-unused in the reference
  const float* Wl = (const float*)d_in[5];
  const float* bl = (const float*)d_in[6];
  float* out = (float*)d_out;
  char* ws = (char*)d_ws;

  f16* embh = (f16*)(ws);                    // 128 MB [B,N,E] fp16
  f16* embt = (f16*)(ws + 134217728L);       // 128 MB [B,E,N] fp16
  f16* Tq = (f16*)(ws + 268435456L);         // 128 MB [B*N,K] fp16; becomes aff in K4
  f16* Mt = (f16*)(ws + 402653184L);         // 512 KB [n][k] fp16
  float* part = (float*)(ws);                // 64 MB, overlays embh (dead after K4)

  hipLaunchKernelGGL(k_gemm_M, dim3(64), dim3(256), 0, stream, Wq, Wk, Mt);
  hipLaunchKernelGGL(k_gather, dim3(32768), dim3(256), 0, stream, tok, temb, embh);
  hipLaunchKernelGGL(k_gatherT, dim3(64, 128), dim3(256), 0, stream, tok, temb, embt);
  hipLaunchKernelGGL(k_gemm_T, dim3(4, 1024), dim3(256), 0, stream, embh, Mt, Tq);
  hipLaunchKernelGGL(k_attn2, dim3(2048), dim3(256), 0, stream, embh, embt, Tq);
  hipLaunchKernelGGL(k_out_partial, dim3(512), dim3(256), 0, stream, Tq, Wl, part);
  hipLaunchKernelGGL(k_reduce, dim3(128), dim3(256), 0, stream, part, bl, out);
}

// Round 3
// 1602.515 us; speedup vs baseline: 1.5323x; 1.3957x over previous
//
#include <hip/hip_runtime.h>

typedef _Float16 f16;
typedef _Float16 half8 __attribute__((ext_vector_type(8)));
typedef _Float16 half4 __attribute__((ext_vector_type(4)));
typedef float floatx4 __attribute__((ext_vector_type(4)));
typedef float floatx16 __attribute__((ext_vector_type(16)));

#define MFMA16(A, B, C) __builtin_amdgcn_mfma_f32_16x16x32_f16((A), (B), (C), 0, 0, 0)
#define MFMA32(A, B, C) __builtin_amdgcn_mfma_f32_32x32x16_f16((A), (B), (C), 0, 0, 0)

// Problem constants: B=128 N=1024 E=512 K=512 DICT=256

// ---------------- K0: Mt[j][i] = sum_k Wq[k][i] * Wk[k][j]  (512x512, fp32 acc -> fp16) -----
__global__ __launch_bounds__(256) void k_gemm_M(const float* __restrict__ Wq,
                                                const float* __restrict__ Wk,
                                                f16* __restrict__ Mt) {
  __shared__ __align__(16) float qa[16][64];
  __shared__ __align__(16) float kbs[16][64];
  const int tid = threadIdx.x;
  const int i0 = (blockIdx.x & 7) * 64;
  const int j0 = (blockIdx.x >> 3) * 64;
  const int tx = tid & 15, ty = tid >> 4;
  float acc[4][4] = {};
  for (int k0 = 0; k0 < 512; k0 += 16) {
    __syncthreads();
    const int kr = tid >> 4;
    const int c4 = (tid & 15) * 4;
    *(float4*)&qa[kr][c4]  = *(const float4*)&Wq[(k0 + kr) * 512 + i0 + c4];
    *(float4*)&kbs[kr][c4] = *(const float4*)&Wk[(k0 + kr) * 512 + j0 + c4];
    __syncthreads();
#pragma unroll
    for (int kk = 0; kk < 16; kk++) {
      float a[4], b[4];
#pragma unroll
      for (int x = 0; x < 4; x++) a[x] = qa[kk][ty * 4 + x];
#pragma unroll
      for (int y = 0; y < 4; y++) b[y] = kbs[kk][tx * 4 + y];
#pragma unroll
      for (int x = 0; x < 4; x++)
#pragma unroll
        for (int y = 0; y < 4; y++) acc[x][y] += a[x] * b[y];
    }
  }
#pragma unroll
  for (int x = 0; x < 4; x++)
#pragma unroll
    for (int y = 0; y < 4; y++)
      Mt[(j0 + tx * 4 + y) * 512 + (i0 + ty * 4 + x)] = (f16)acc[x][y];
}

// ---------------- K1: emb_h[b,n,e] = fp16(tok_emb[tok[b,n], e]) --------------------------
__global__ __launch_bounds__(256) void k_gather(const int* __restrict__ tok,
                                                const float* __restrict__ temb,
                                                f16* __restrict__ embh) {
  const long g = (long)blockIdx.x * 256 + threadIdx.x;
  const long flat = g * 8;
  const int row = (int)(flat >> 9);
  const int e0 = (int)(flat & 511);
  const int t = tok[row];
  const float4 v0 = *(const float4*)&temb[t * 512 + e0];
  const float4 v1 = *(const float4*)&temb[t * 512 + e0 + 4];
  half8 h;
  h[0] = (f16)v0.x; h[1] = (f16)v0.y; h[2] = (f16)v0.z; h[3] = (f16)v0.w;
  h[4] = (f16)v1.x; h[5] = (f16)v1.y; h[6] = (f16)v1.z; h[7] = (f16)v1.w;
  *(half8*)&embh[flat] = h;
}

// ---------------- K2: emb_t[b,e,n] = fp16(tok_emb[tok[b,n], e])  (transposed) -------------
__global__ __launch_bounds__(256) void k_gatherT(const int* __restrict__ tok,
                                                 const float* __restrict__ temb,
                                                 f16* __restrict__ embt) {
  __shared__ int tl[64];
  const int b = blockIdx.y;
  const int n0 = (blockIdx.x & 15) * 64;
  const int e0 = (blockIdx.x >> 4) * 128;
  const int tid = threadIdx.x;
  if (tid < 64) tl[tid] = tok[b * 1024 + n0 + tid];
  __syncthreads();
  const int n8 = (tid & 7) * 8;
  const int e4 = e0 + (tid >> 3) * 4;
  float4 v[8];
#pragma unroll
  for (int j = 0; j < 8; j++) v[j] = *(const float4*)&temb[tl[n8 + j] * 512 + e4];
#pragma unroll
  for (int a = 0; a < 4; a++) {
    half8 h;
#pragma unroll
    for (int j = 0; j < 8; j++) h[j] = (f16)((&v[j].x)[a]);
    *(half8*)&embt[(((long)(b * 512 + e4 + a)) << 10) + n0 + n8] = h;
  }
}

// ---------------- K3: T = emb_h[131072x512] @ M[512x512] -> fp16 (Mt is [n][k]) -----------
__global__ __launch_bounds__(256) void k_gemm_T(const f16* __restrict__ A,
                                                const f16* __restrict__ Bt,
                                                f16* __restrict__ T) {
  __shared__ __align__(16) f16 smem[17408];
  f16* As = smem;          // 128 rows x 40 halves
  f16* Bs = smem + 5120;   // 128 rows x 40 halves
  const int tid = threadIdx.x;
  const long m0 = (long)blockIdx.y * 128;
  const int n0 = blockIdx.x * 128;
  const int w = tid >> 6, lane = tid & 63, lq = lane & 15, quad = lane >> 4;
  const int wm = w >> 1, wn = w & 1;
  floatx4 acc[4][4] = {};
  const int sr = tid >> 1, shc = (tid & 1) * 16;
  for (int k0 = 0; k0 < 512; k0 += 32) {
    half8 a0 = *(const half8*)&A[(m0 + sr) * 512 + k0 + shc];
    half8 a1 = *(const half8*)&A[(m0 + sr) * 512 + k0 + shc + 8];
    half8 b0 = *(const half8*)&Bt[(long)(n0 + sr) * 512 + k0 + shc];
    half8 b1 = *(const half8*)&Bt[(long)(n0 + sr) * 512 + k0 + shc + 8];
    __syncthreads();
    *(half8*)&As[sr * 40 + shc] = a0;
    *(half8*)&As[sr * 40 + shc + 8] = a1;
    *(half8*)&Bs[sr * 40 + shc] = b0;
    *(half8*)&Bs[sr * 40 + shc + 8] = b1;
    __syncthreads();
    half8 af[4], bf[4];
#pragma unroll
    for (int mt = 0; mt < 4; mt++) af[mt] = *(half8*)&As[(wm * 64 + mt * 16 + lq) * 40 + quad * 8];
#pragma unroll
    for (int nt = 0; nt < 4; nt++) bf[nt] = *(half8*)&Bs[(wn * 64 + nt * 16 + lq) * 40 + quad * 8];
#pragma unroll
    for (int mt = 0; mt < 4; mt++)
#pragma unroll
      for (int nt = 0; nt < 4; nt++) acc[mt][nt] = MFMA16(af[mt], bf[nt], acc[mt][nt]);
  }
  __syncthreads();
  f16* Cp = smem;
#pragma unroll
  for (int mt = 0; mt < 4; mt++)
#pragma unroll
    for (int nt = 0; nt < 4; nt++)
#pragma unroll
      for (int rr = 0; rr < 4; rr++)
        Cp[(wm * 64 + mt * 16 + quad * 4 + rr) * 136 + wn * 64 + nt * 16 + lq] =
            (f16)acc[mt][nt][rr];
  __syncthreads();
  const int orow = tid >> 1, occ = (tid & 1) * 64;
#pragma unroll
  for (int i = 0; i < 8; i++) {
    half8 hv = *(half8*)&Cp[orow * 136 + occ + i * 8];
    *(half8*)&T[(m0 + orow) * 512 + n0 + occ + i * 8] = hv;
  }
}

// ---------------- K4 v3: causal flash attention ------------------------------------------
// Q-tile 64 staged in LDS (swizzled); K/V fragments read DIRECTLY from L2-resident
// embh/embt. 2 barriers/iter (softmax exchange only). LDS ~77 KB -> 2 blocks/CU.
// Each block processes paired q-tiles (p, 15-p): uniform 17 k-iters.
__global__ __launch_bounds__(256, 2) void k_attn3(const f16* __restrict__ embh,
                                                  const f16* __restrict__ embt,
                                                  f16* tq_aff) {
  __shared__ __align__(16) f16 smem[37888];  // Qs[64*512] swizzled | Pl at +32768 [64][72]
  __shared__ __align__(16) float wmax[4][32];
  __shared__ __align__(16) float wsum[4][32];
  __shared__ __align__(16) float alpha_s[64];
  __shared__ __align__(16) float l_s[64];
  f16* Qs = smem;
  f16* Pl = smem + 32768;

  const int tid = threadIdx.x;
  const int w = tid >> 6, lane = tid & 63;
  const int l31 = lane & 31, lh = lane >> 5;
  const int mh = w & 1, nh = w >> 1;

  // XCD swizzle: 8 consecutive slots per XCD = one batch's 8 pair-blocks
  const int bid = blockIdx.x;
  const int xcd = bid & 7, idx = bid >> 3;
  const int b = xcd * 16 + (idx >> 3);
  const int pair = idx & 7;
  const long bOff = (long)b * 1024 * 512;

  const int qrow = nh * 32 + l31;  // q-row within tile for QK B-frags

  for (int t = 0; t < 2; t++) {
    const int qb = t ? (15 - pair) : pair;
    const int q0 = qb * 64;
    __syncthreads();  // protect Qs/Ob region from prior tile's readers
    {  // stage Qs: row=tid&63, quarter=tid>>6, xor-swizzled 16B chunks
      const int row = tid & 63, qo = tid >> 6;
      const f16* src = &tq_aff[bOff + (long)(q0 + row) * 512];
#pragma unroll
      for (int i = 0; i < 16; i++) {
        int g = qo * 16 + i;
        int gs = (g & ~7) | ((g ^ row) & 7);
        *(half8*)&Qs[row * 512 + gs * 8] = *(const half8*)&src[g * 8];
      }
    }
    __syncthreads();  // Qs ready

    floatx16 Oa[2][4];  // O[64q][128e] per wave (e-slice w*128): [q-half][e-sub]
#pragma unroll
    for (int mt = 0; mt < 2; mt++)
#pragma unroll
      for (int nt = 0; nt < 4; nt++) Oa[mt][nt] = (floatx16)(0.f);
    float mrow = -1e30f, lrow = 0.f;
    const int qcol = q0 + nh * 32 + l31;

    for (int kb = 0; kb <= qb; kb++) {
      // ---- QK: S^T quadrant [32key x 32q]; A-frags from global embh, B-frags from Qs
      const f16* kptr = &embh[bOff + (long)(kb * 64 + mh * 32 + l31) * 512 + lh * 8];
      floatx16 st = {};
#pragma unroll
      for (int kc8 = 0; kc8 < 4; kc8++) {
        half8 a[8], bq[8];
#pragma unroll
        for (int i = 0; i < 8; i++) {
          const int kc = kc8 * 8 + i;
          a[i] = *(const half8*)&kptr[kc * 16];
          const int g = kc * 2 + lh;
          const int gs = (g & ~7) | ((g ^ qrow) & 7);
          bq[i] = *(half8*)&Qs[qrow * 512 + gs * 8];
        }
#pragma unroll
        for (int i = 0; i < 8; i++) st = MFMA32(a[i], bq[i], st);
      }
      // ---- mask + per-lane partial max (lane holds 16 keys for q=qcol)
      float sv[16];
      float pm = -1e30f;
#pragma unroll
      for (int r = 0; r < 16; r++) {
        int keyr = kb * 64 + mh * 32 + (r & 3) + 8 * (r >> 2) + 4 * lh;
        float s = st[r];
        if (keyr > qcol) s = -1e30f;
        sv[r] = s;
        pm = fmaxf(pm, s);
      }
      pm = fmaxf(pm, __shfl_xor(pm, 32, 64));
      if (lane < 32) wmax[w][lane] = pm;
      __syncthreads();  // C: partial maxima exchanged (also: prior PV's Pl reads done)
      const float tmax = fmaxf(wmax[nh * 2][l31], wmax[nh * 2 + 1][l31]);
      const float mnew = fmaxf(mrow, tmax);
      const float al = exp2f((mrow - mnew) * 1.44269504f);
      float psum = 0.f;
      f16 ph[16];
#pragma unroll
      for (int r = 0; r < 16; r++) {
        float p = exp2f((sv[r] - mnew) * 1.44269504f);
        psum += p;
        ph[r] = (f16)p;
      }
      psum += __shfl_xor(psum, 32, 64);
      if (lane < 32) wsum[w][lane] = psum;
      if (mh == 0 && lane < 32) alpha_s[nh * 32 + lane] = al;
#pragma unroll
      for (int grp = 0; grp < 4; grp++) {
        half4 hp = {ph[grp * 4 + 0], ph[grp * 4 + 1], ph[grp * 4 + 2], ph[grp * 4 + 3]};
        *(half4*)&Pl[(nh * 32 + l31) * 72 + mh * 32 + grp * 8 + lh * 4] = hp;
      }
      mrow = mnew;
      __syncthreads();  // D: P / wsum / alpha ready
      lrow = lrow * al + wsum[nh * 2][l31] + wsum[nh * 2 + 1][l31];
      // ---- rescale O by alpha
#pragma unroll
      for (int mt = 0; mt < 2; mt++)
#pragma unroll
        for (int grp = 0; grp < 4; grp++) {
          floatx4 av = *(floatx4*)&alpha_s[mt * 32 + grp * 8 + lh * 4];
#pragma unroll
          for (int nt = 0; nt < 4; nt++)
#pragma unroll
            for (int j = 0; j < 4; j++) Oa[mt][nt][grp * 4 + j] *= av[j];
        }
      // ---- PV: O[64q][128e] += P @ V; A-frags from Pl, B-frags from global embt
#pragma unroll
      for (int kc = 0; kc < 4; kc++) {
        half8 ap0 = *(half8*)&Pl[l31 * 72 + kc * 16 + lh * 8];
        half8 ap1 = *(half8*)&Pl[(32 + l31) * 72 + kc * 16 + lh * 8];
#pragma unroll
        for (int nt = 0; nt < 4; nt++) {
          const int e = w * 128 + nt * 32 + l31;
          half8 bv = *(const half8*)&embt[((long)(b * 512 + e) << 10) + kb * 64 +
                                          kc * 16 + lh * 8];
          Oa[0][nt] = MFMA32(ap0, bv, Oa[0][nt]);
          Oa[1][nt] = MFMA32(ap1, bv, Oa[1][nt]);
        }
      }
    }
    // ---- epilogue: divide by l, pack f16 via LDS (overlays Qs), coalesced write
    if (mh == 0 && lane < 32) l_s[nh * 32 + lane] = lrow;
    __syncthreads();  // E: all PV done, l_s ready; Qs dead
    f16* Ob = smem;   // [64][520]
#pragma unroll
    for (int mt = 0; mt < 2; mt++)
#pragma unroll
      for (int grp = 0; grp < 4; grp++) {
        floatx4 lv = *(floatx4*)&l_s[mt * 32 + grp * 8 + lh * 4];
#pragma unroll
        for (int nt = 0; nt < 4; nt++) {
          const int col = w * 128 + nt * 32 + l31;
#pragma unroll
          for (int j = 0; j < 4; j++) {
            const int row = mt * 32 + grp * 8 + lh * 4 + j;
            Ob[row * 520 + col] = (f16)(Oa[mt][nt][grp * 4 + j] / lv[j]);
          }
        }
      }
    __syncthreads();  // Ob ready
    {
      const int row = tid >> 2, seg = tid & 3;
#pragma unroll
      for (int i = 0; i < 16; i++) {
        half8 v = *(half8*)&Ob[row * 520 + seg * 128 + i * 8];
        *(half8*)&tq_aff[bOff + (long)(q0 + row) * 512 + seg * 128 + i * 8] = v;
      }
    }
  }
}

// ---------------- K5: split-K output GEMM: partial[blk] = aff[:,chunk] @ Wl[:,chunk]^T ----
__global__ __launch_bounds__(256) void k_out_partial(const f16* __restrict__ aff,
                                                     const float* __restrict__ Wl,
                                                     float* __restrict__ part) {
  __shared__ __align__(16) f16 smem[15360];
  f16* As = smem;
  f16* Bs = smem + 5120;
  const int tid = threadIdx.x;
  const int w = tid >> 6, lane = tid & 63, lq = lane & 15, quad = lane >> 4;
  const int wm = w >> 1, wn = w & 1;
  const long kbase = (long)blockIdx.x * 1024;
  floatx4 acc[4][8] = {};
  const int rA = tid >> 1, hcA = (tid & 1) * 16;
  const int rB = tid >> 3, cB = (tid & 7) * 4;  // coalesced B-stage: 8 lanes x 16B per row
  for (int k0 = 0; k0 < 1024; k0 += 32) {
    const long kk = kbase + k0;
    half8 a0 = *(const half8*)&aff[(long)rA * 524288 + kk + hcA];
    half8 a1 = *(const half8*)&aff[(long)rA * 524288 + kk + hcA + 8];
    float4 bv[8];
#pragma unroll
    for (int pass = 0; pass < 8; pass++)
      bv[pass] = *(const float4*)&Wl[(long)(pass * 32 + rB) * 524288 + kk + cB];
    __syncthreads();
    *(half8*)&As[rA * 40 + hcA] = a0;
    *(half8*)&As[rA * 40 + hcA + 8] = a1;
#pragma unroll
    for (int pass = 0; pass < 8; pass++) {
      half4 hb = {(f16)bv[pass].x, (f16)bv[pass].y, (f16)bv[pass].z, (f16)bv[pass].w};
      *(half4*)&Bs[(pass * 32 + rB) * 40 + cB] = hb;
    }
    __syncthreads();
    half8 af[4], bf[8];
#pragma unroll
    for (int mt = 0; mt < 4; mt++) af[mt] = *(half8*)&As[(wm * 64 + mt * 16 + lq) * 40 + quad * 8];
#pragma unroll
    for (int nt = 0; nt < 8; nt++) bf[nt] = *(half8*)&Bs[(wn * 128 + nt * 16 + lq) * 40 + quad * 8];
#pragma unroll
    for (int mt = 0; mt < 4; mt++)
#pragma unroll
      for (int nt = 0; nt < 8; nt++) acc[mt][nt] = MFMA16(af[mt], bf[nt], acc[mt][nt]);
  }
  float* po = part + (long)blockIdx.x * 32768;
#pragma unroll
  for (int mt = 0; mt < 4; mt++)
#pragma unroll
    for (int nt = 0; nt < 8; nt++)
#pragma unroll
      for (int rr = 0; rr < 4; rr++)
        po[(wm * 64 + mt * 16 + quad * 4 + rr) * 256 + wn * 128 + nt * 16 + lq] =
            acc[mt][nt][rr];
}

// ---------------- K6: out = sum_p partial[p] + b_lin -------------------------------------
__global__ __launch_bounds__(256) void k_reduce(const float* __restrict__ part,
                                                const float* __restrict__ bl,
                                                float* __restrict__ out) {
  const int idx = blockIdx.x * 256 + threadIdx.x;
  float s = bl[idx & 255];
  for (int p = 0; p < 512; p++) s += part[(long)p * 32768 + idx];
  out[idx] = s;
}

extern "C" void kernel_launch(void* const* d_in, const int* in_sizes, int n_in,
                              void* d_out, int out_size, void* d_ws, size_t ws_size,
                              hipStream_t stream) {
  (void)in_sizes; (void)n_in; (void)out_size; (void)ws_size;
  const int* tok = (const int*)d_in[0];
  const float* temb = (const float*)d_in[1];
  const float* Wq = (const float*)d_in[2];
  const float* Wk = (const float*)d_in[3];
  // d_in[4] = Wv : computed-but-unused in the reference
  const float* Wl = (const float*)d_in[5];
  const float* bl = (const float*)d_in[6];
  float* out = (float*)d_out;
  char* ws = (char*)d_ws;

  f16* embh = (f16*)(ws);                    // 128 MB [B,N,E] fp16
  f16* embt = (f16*)(ws + 134217728L);       // 128 MB [B,E,N] fp16
  f16* Tq = (f16*)(ws + 268435456L);         // 128 MB [B*N,K] fp16; becomes aff in K4
  f16* Mt = (f16*)(ws + 402653184L);         // 512 KB [n][k] fp16
  float* part = (float*)(ws);                // 64 MB, overlays embh (dead after K4)

  hipLaunchKernelGGL(k_gemm_M, dim3(64), dim3(256), 0, stream, Wq, Wk, Mt);
  hipLaunchKernelGGL(k_gather, dim3(32768), dim3(256), 0, stream, tok, temb, embh);
  hipLaunchKernelGGL(k_gatherT, dim3(64, 128), dim3(256), 0, stream, tok, temb, embt);
  hipLaunchKernelGGL(k_gemm_T, dim3(4, 1024), dim3(256), 0, stream, embh, Mt, Tq);
  hipLaunchKernelGGL(k_attn3, dim3(1024), dim3(256), 0, stream, embh, embt, Tq);
  hipLaunchKernelGGL(k_out_partial, dim3(512), dim3(256), 0, stream, Tq, Wl, part);
  hipLaunchKernelGGL(k_reduce, dim3(128), dim3(256), 0, stream, part, bl, out);
}